// Round 1
// baseline (488.632 us; speedup 1.0000x reference)
//
#include <hip/hip_runtime.h>
#include <hip/hip_bf16.h>

#define HH 256
#define WW 256
#define AA 5
#define NCLS 80
#define NROW (HH*WW*AA)        // 327680
#define ROWS_PER_BLOCK 128
#define K_TARGET 1024u
#define CAP 4096u
#define MAX_OUT 100

// ---------------- workspace layout (bytes) ----------------
// boxes   : float4[NROW]            @ 0         (5,242,880)
// scores  : float [NROW]            @ 5,242,880 (1,310,720)
// classes : int   [NROW]            @ 6,553,600 (1,310,720)
// hist    : uint  [65536]           @ 7,864,320 (  262,144)
// counters: uint  [16]              @ 8,126,464 (       64)   <- memset together with hist
// keys    : ull   [CAP]             @ 8,126,528 (   32,768)
#define WS_BOXES    0
#define WS_SCORES   5242880
#define WS_CLASSES  6553600
#define WS_HIST     7864320
#define WS_COUNTERS 8126464
#define WS_KEYS     8126528

// ---------------------------------------------------------------------------
// Kernel 1: decode + score + class + histogram of score bits (top 16)
// ---------------------------------------------------------------------------
__global__ __launch_bounds__(ROWS_PER_BLOCK) void decode_kernel(
    const float* __restrict__ x, const float* __restrict__ anchors,
    float4* __restrict__ boxes, float* __restrict__ scores,
    int* __restrict__ classes, unsigned* __restrict__ hist) {
  __shared__ float lds[ROWS_PER_BLOCK * 85];
  const int row0 = blockIdx.x * ROWS_PER_BLOCK;

  // coalesced float4 staging: block's region is 128*85*4 = 43520 B, 16B aligned
  {
    const float4* src4 = (const float4*)(x + (size_t)row0 * 85);
    float4* dst4 = (float4*)lds;
    const int nvec = ROWS_PER_BLOCK * 85 / 4;  // 2720
    for (int i = threadIdx.x; i < nvec; i += ROWS_PER_BLOCK) dst4[i] = src4[i];
  }
  __syncthreads();

  const int tid = threadIdx.x;
  const float* row = lds + tid * 85;   // stride 85 words: gcd(85,32)=1 -> conflict-free
  const int r = row0 + tid;

  // argmax of logits (first occurrence) — equals argmax of conf*softmax
  float m = row[5]; int am = 0;
  for (int c = 1; c < NCLS; ++c) { float l = row[5 + c]; if (l > m) { m = l; am = c; } }
  // softmax denominator, same op order as reference (sequential fp32 sum)
  float s = 0.f;
  for (int c = 0; c < NCLS; ++c) s += expf(row[5 + c] - m);
  float conf = 1.f / (1.f + expf(-row[4]));
  float p = 1.f / s;            // == fl(exp(0)/s), matching reference's max softmax prob
  float best = conf * p;
  float score; int cls;
  if (best > 0.01f) { score = best; cls = am; } else { score = 0.f; cls = 0; }

  const int a  = r % AA;
  const int hw = r / AA;
  const float wf = (float)(hw % WW);
  const float hf = (float)(hw / WW);
  float sx = 1.f / (1.f + expf(-row[0]));
  float sy = 1.f / (1.f + expf(-row[1]));
  float xc = (sx + wf) / 256.f;
  float yc = (sy + hf) / 256.f;
  float bw = expf(row[2]) * anchors[2*a]     / 256.f;
  float bh = expf(row[3]) * anchors[2*a + 1] / 256.f;
  float hwd = bw / 2.f, hhd = bh / 2.f;

  boxes[r]   = make_float4(xc - hwd, yc - hhd, xc + hwd, yc + hhd);
  scores[r]  = score;
  classes[r] = cls;
  if (score > 0.f) atomicAdd(&hist[__float_as_uint(score) >> 16], 1u);
}

// ---------------------------------------------------------------------------
// Kernel 2: find score-bits threshold T so that ~K_TARGET candidates pass
// ---------------------------------------------------------------------------
__global__ __launch_bounds__(1024) void thresh_kernel(
    const unsigned* __restrict__ hist, unsigned* __restrict__ counters) {
  __shared__ unsigned csum[1024];
  const int tid = threadIdx.x;
  unsigned s = 0;
  for (int b = 0; b < 64; ++b) s += hist[tid * 64 + b];
  csum[tid] = s;
  __syncthreads();
  if (tid == 0) {
    unsigned cum = 0; unsigned T = 0;
    for (int j = 1023; j >= 0; --j) {
      if (cum + csum[j] >= K_TARGET) {
        for (int b = 63; b >= 0; --b) {
          cum += hist[j * 64 + b];
          if (cum >= K_TARGET) {
            T = (unsigned)(j * 64 + b);
            if (cum > CAP) T += 1;   // fall back to the stricter bin if overflow
            break;
          }
        }
        break;
      }
      cum += csum[j];
    }
    counters[1] = T;
  }
}

// ---------------------------------------------------------------------------
// Kernel 3: compact candidates (score bits >= T) into packed sort keys
// ---------------------------------------------------------------------------
__global__ __launch_bounds__(256) void compact_kernel(
    const float* __restrict__ scores, unsigned* __restrict__ counters,
    unsigned long long* __restrict__ keys) {
  int r = blockIdx.x * 256 + threadIdx.x;
  if (r >= NROW) return;
  float s = scores[r];
  if (s <= 0.f) return;
  unsigned bits = __float_as_uint(s);
  if ((bits >> 16) < counters[1]) return;
  unsigned pos = atomicAdd(&counters[0], 1u);
  if (pos < CAP)
    keys[pos] = ((unsigned long long)bits << 32) |
                (unsigned long long)(0xFFFFFFFFu - (unsigned)r);
}

// ---------------------------------------------------------------------------
// Kernel 4: single-block bitonic sort (desc) + greedy NMS scan + output
// ---------------------------------------------------------------------------
__global__ __launch_bounds__(256) void nms_kernel(
    const float4* __restrict__ boxes, const int* __restrict__ classes,
    const unsigned long long* __restrict__ keys,
    const unsigned* __restrict__ counters, float* __restrict__ out) {
  __shared__ unsigned long long sk[CAP];
  __shared__ float4 kbox[MAX_OUT];
  __shared__ float  kscore[MAX_OUT];
  __shared__ int    krow[MAX_OUT];
  __shared__ int    knum;
  const int tid = threadIdx.x;

  unsigned n = counters[0]; if (n > CAP) n = CAP;
  unsigned npow2 = 2; while (npow2 < n) npow2 <<= 1;

  for (unsigned i = tid; i < npow2; i += 256) sk[i] = (i < n) ? keys[i] : 0ull;
  __syncthreads();

  // bitonic sort, descending (key = score_bits<<32 | (~idx) -> stable argmax order)
  for (unsigned k = 2; k <= npow2; k <<= 1) {
    for (unsigned j = k >> 1; j > 0; j >>= 1) {
      for (unsigned i = tid; i < npow2; i += 256) {
        unsigned ixj = i ^ j;
        if (ixj > i) {
          unsigned long long a = sk[i], b = sk[ixj];
          bool desc = ((i & k) == 0);
          if (desc ? (a < b) : (a > b)) { sk[i] = b; sk[ixj] = a; }
        }
      }
      __syncthreads();
    }
  }

  // greedy scan: wave 0 only, kept boxes live in lane registers (slots tid, tid+64)
  if (tid < 64) {
    int nk = 0;
    float ax1=0,ay1=0,ax2=0,ay2=0,aar=0;
    float bx1=0,by1=0,bx2=0,by2=0,bar=0;
    for (unsigned c = 0; c < n && nk < MAX_OUT; ++c) {
      unsigned long long key = sk[c];
      unsigned sbits = (unsigned)(key >> 32);
      if (sbits == 0u) break;
      unsigned r = 0xFFFFFFFFu - (unsigned)(key & 0xFFFFFFFFull);
      float4 bb = boxes[r];
      float area = (bb.z - bb.x) * (bb.w - bb.y);
      bool s0 = false, s1 = false;
      if (tid < nk) {
        float xx1 = fmaxf(ax1, bb.x), yy1 = fmaxf(ay1, bb.y);
        float xx2 = fminf(ax2, bb.z), yy2 = fminf(ay2, bb.w);
        float inter = fmaxf(xx2 - xx1, 0.f) * fmaxf(yy2 - yy1, 0.f);
        float uni = aar + area - inter;
        float iou = (uni > 0.f) ? (inter / uni) : 0.f;
        s0 = iou > 0.5f;
      }
      if (tid + 64 < nk) {
        float xx1 = fmaxf(bx1, bb.x), yy1 = fmaxf(by1, bb.y);
        float xx2 = fminf(bx2, bb.z), yy2 = fminf(by2, bb.w);
        float inter = fmaxf(xx2 - xx1, 0.f) * fmaxf(yy2 - yy1, 0.f);
        float uni = bar + area - inter;
        float iou = (uni > 0.f) ? (inter / uni) : 0.f;
        s1 = iou > 0.5f;
      }
      if (!__any(s0 || s1)) {
        if (tid == nk)      { ax1=bb.x; ay1=bb.y; ax2=bb.z; ay2=bb.w; aar=area; }
        if (tid == nk - 64) { bx1=bb.x; by1=bb.y; bx2=bb.z; by2=bb.w; bar=area; }
        if (tid == 0) { kbox[nk] = bb; kscore[nk] = __uint_as_float(sbits); krow[nk] = (int)r; }
        ++nk;
      }
    }
    if (tid == 0) knum = nk;
  }
  __syncthreads();

  // outputs: [0..99] conf, [100..499] boxes (100,4), [500..599] classes (as float)
  if (tid < MAX_OUT) {
    float conf = 0.f; float4 bb = make_float4(0.f, 0.f, 0.f, 0.f); float cf = -1.f;
    if (tid < knum) { conf = kscore[tid]; bb = kbox[tid]; cf = (float)classes[krow[tid]]; }
    out[tid] = conf;
    ((float4*)(out + 100))[tid] = bb;
    out[500 + tid] = cf;
  }
}

// ---------------------------------------------------------------------------
extern "C" void kernel_launch(void* const* d_in, const int* in_sizes, int n_in,
                              void* d_out, int out_size, void* d_ws, size_t ws_size,
                              hipStream_t stream) {
  const float* x       = (const float*)d_in[0];
  const float* anchors = (const float*)d_in[1];
  float* out = (float*)d_out;
  char* ws = (char*)d_ws;

  float4*             boxes    = (float4*)(ws + WS_BOXES);
  float*              scores   = (float*)(ws + WS_SCORES);
  int*                classes  = (int*)(ws + WS_CLASSES);
  unsigned*           hist     = (unsigned*)(ws + WS_HIST);
  unsigned*           counters = (unsigned*)(ws + WS_COUNTERS);
  unsigned long long* keys     = (unsigned long long*)(ws + WS_KEYS);

  // zero hist + counters (contiguous region), graph-capture safe
  hipMemsetAsync(hist, 0, 65536 * sizeof(unsigned) + 64, stream);

  hipLaunchKernelGGL(decode_kernel, dim3(NROW / ROWS_PER_BLOCK), dim3(ROWS_PER_BLOCK),
                     0, stream, x, anchors, boxes, scores, classes, hist);
  hipLaunchKernelGGL(thresh_kernel, dim3(1), dim3(1024), 0, stream, hist, counters);
  hipLaunchKernelGGL(compact_kernel, dim3((NROW + 255) / 256), dim3(256),
                     0, stream, scores, counters, keys);
  hipLaunchKernelGGL(nms_kernel, dim3(1), dim3(256), 0, stream,
                     boxes, classes, keys, counters, out);
}

// Round 2
// 423.092 us; speedup vs baseline: 1.1549x; 1.1549x over previous
//
#include <hip/hip_runtime.h>
#include <hip/hip_bf16.h>

#define HH 256
#define WW 256
#define AA 5
#define NCLS 80
#define NROW (HH*WW*AA)        // 327680
#define ROWS_PER_BLOCK 128
#define K_TARGET 1024u
#define CAP 2048u
#define MAX_OUT 100

// ---------------- workspace layout (bytes) ----------------
#define WS_BOXES    0           // float4[NROW]  5,242,880
#define WS_SCORES   5242880     // float [NROW]  1,310,720
#define WS_CLASSES  6553600     // int   [NROW]  1,310,720
#define WS_HIST     7864320     // uint  [65536]   262,144
#define WS_COUNTERS 8126464     // uint  [16]           64
#define WS_KEYS     8126528     // ull   [CAP]      16,384

typedef __attribute__((address_space(1))) const unsigned int g_uint;
typedef __attribute__((address_space(3))) unsigned int lds_uint;

__device__ __forceinline__ void async_copy16(const float* g, float* l) {
  __builtin_amdgcn_global_load_lds((const g_uint*)g, (lds_uint*)l, 16, 0, 0);
}

// ---------------------------------------------------------------------------
// Kernel 1: decode + score + class + histogram of score bits (top 16)
// Staging via global_load_lds (16B): wave issues all transfers back-to-back,
// fixing the R1 MLP starvation (294 GB/s observed with VGPR round-trip).
// ---------------------------------------------------------------------------
__global__ __launch_bounds__(ROWS_PER_BLOCK) void decode_kernel(
    const float* __restrict__ x, const float* __restrict__ anchors,
    float4* __restrict__ boxes, float* __restrict__ scores,
    int* __restrict__ classes, unsigned* __restrict__ hist) {
  __shared__ float lds[ROWS_PER_BLOCK * 85];
  const int row0 = blockIdx.x * ROWS_PER_BLOCK;
  const int tid = threadIdx.x;

  // block region: 128*85*4 = 43520 B = 2720 x 16B, 16B-aligned
  {
    const float* gbase = x + (size_t)row0 * 85;
    #pragma unroll
    for (int i = 0; i < 21; ++i) {
      int idx = i * ROWS_PER_BLOCK + tid;
      async_copy16(gbase + idx * 4, lds + idx * 4);
    }
    if (tid < 32) {  // tail: 2720 - 21*128 = 32 transfers
      int idx = 21 * ROWS_PER_BLOCK + tid;
      async_copy16(gbase + idx * 4, lds + idx * 4);
    }
  }
  __syncthreads();

  const float* row = lds + tid * 85;   // stride 85: gcd(85,32)=1 -> conflict-free
  const int r = row0 + tid;

  // argmax of logits (first occurrence) == argmax of conf*softmax
  float m = row[5]; int am = 0;
  for (int c = 1; c < NCLS; ++c) { float l = row[5 + c]; if (l > m) { m = l; am = c; } }
  // sequential fp32 softmax denominator (bit-exact vs R1 which matched ref)
  float s = 0.f;
  for (int c = 0; c < NCLS; ++c) s += expf(row[5 + c] - m);
  float conf = 1.f / (1.f + expf(-row[4]));
  float p = 1.f / s;            // == fl(exp(0)/s) at the argmax
  float best = conf * p;
  float score; int cls;
  if (best > 0.01f) { score = best; cls = am; } else { score = 0.f; cls = 0; }

  const int a  = r % AA;
  const int hw = r / AA;
  const float wf = (float)(hw % WW);
  const float hf = (float)(hw / WW);
  float sx = 1.f / (1.f + expf(-row[0]));
  float sy = 1.f / (1.f + expf(-row[1]));
  float xc = (sx + wf) / 256.f;
  float yc = (sy + hf) / 256.f;
  float bw = expf(row[2]) * anchors[2*a]     / 256.f;
  float bh = expf(row[3]) * anchors[2*a + 1] / 256.f;
  float hwd = bw / 2.f, hhd = bh / 2.f;

  boxes[r]   = make_float4(xc - hwd, yc - hhd, xc + hwd, yc + hhd);
  scores[r]  = score;
  classes[r] = cls;
  if (score > 0.f) atomicAdd(&hist[__float_as_uint(score) >> 16], 1u);
}

// ---------------------------------------------------------------------------
// Kernel 2: threshold via parallel suffix scan (1024 chunks of 64 bins)
// ---------------------------------------------------------------------------
__global__ __launch_bounds__(1024) void thresh_kernel(
    const unsigned* __restrict__ hist, unsigned* __restrict__ counters) {
  __shared__ unsigned bufA[1024], bufB[1024];
  __shared__ unsigned chunkbins[64];
  __shared__ int cstar;
  const int t = threadIdx.x;
  if (t == 0) cstar = -1;

  // chunk sum: 16 x uint4 per thread
  unsigned s = 0;
  const uint4* h4 = (const uint4*)(hist + t * 64);
  #pragma unroll
  for (int i = 0; i < 16; ++i) { uint4 v = h4[i]; s += v.x + v.y + v.z + v.w; }
  bufA[t] = s;
  __syncthreads();

  // Hillis-Steele suffix sums: sfx[t] = sum_{j>=t} chunk[j]
  unsigned* src = bufA; unsigned* dst = bufB;
  for (int d = 1; d < 1024; d <<= 1) {
    unsigned v = src[t] + ((t + d < 1024) ? src[t + d] : 0u);
    dst[t] = v;
    __syncthreads();
    unsigned* tmp = src; src = dst; dst = tmp;
  }
  // crossing chunk: largest c with sfx[c] >= K
  if (src[t] >= K_TARGET && (t == 1023 || src[t + 1] < K_TARGET)) cstar = t;
  __syncthreads();
  int c = cstar;
  if (c >= 0 && t < 64) chunkbins[t] = hist[c * 64 + t];
  __syncthreads();

  if (t == 0) {
    unsigned T = 0;
    if (c >= 0) {
      unsigned cum = (c == 1023) ? 0u : src[c + 1];
      for (int b = 63; b >= 0; --b) {
        cum += chunkbins[b];
        if (cum >= K_TARGET) {
          T = (unsigned)(c * 64 + b);
          if (cum > CAP) T += 1;  // stricter bin; residual < K_TARGET <= CAP
          break;
        }
      }
    }
    counters[1] = T;
  }
}

// ---------------------------------------------------------------------------
// Kernel 3: compact candidates (score bits >= T), 4 rows/thread via float4
// ---------------------------------------------------------------------------
__global__ __launch_bounds__(256) void compact_kernel(
    const float* __restrict__ scores, unsigned* __restrict__ counters,
    unsigned long long* __restrict__ keys) {
  int i = blockIdx.x * 256 + threadIdx.x;     // [0, NROW/4)
  float4 s4 = ((const float4*)scores)[i];
  unsigned T = counters[1];
  float sv[4] = {s4.x, s4.y, s4.z, s4.w};
  #pragma unroll
  for (int k = 0; k < 4; ++k) {
    float s = sv[k];
    if (s <= 0.f) continue;
    unsigned bits = __float_as_uint(s);
    if ((bits >> 16) < T) continue;
    unsigned pos = atomicAdd(&counters[0], 1u);
    if (pos < CAP) {
      unsigned r = (unsigned)(4 * i + k);
      keys[pos] = ((unsigned long long)bits << 32) |
                  (unsigned long long)(0xFFFFFFFFu - r);
    }
  }
}

// ---------------------------------------------------------------------------
// Kernel 4: single-block bitonic sort (desc) + LDS box prefetch + greedy NMS
// ---------------------------------------------------------------------------
__global__ __launch_bounds__(256) void nms_kernel(
    const float4* __restrict__ boxes, const int* __restrict__ classes,
    const unsigned long long* __restrict__ keys,
    const unsigned* __restrict__ counters, float* __restrict__ out) {
  __shared__ unsigned long long sk[CAP];   // 16 KB
  __shared__ float4 cbox[CAP];             // 32 KB
  __shared__ float4 kbox[MAX_OUT];
  __shared__ float  kscore[MAX_OUT];
  __shared__ int    krow[MAX_OUT];
  __shared__ int    knum;
  const int tid = threadIdx.x;

  unsigned n = counters[0]; if (n > CAP) n = CAP;
  unsigned npow2 = 2; while (npow2 < n) npow2 <<= 1;

  for (unsigned i = tid; i < npow2; i += 256) sk[i] = (i < n) ? keys[i] : 0ull;
  __syncthreads();

  // bitonic sort, descending (key = score_bits<<32 | ~idx -> stable argmax order)
  for (unsigned k = 2; k <= npow2; k <<= 1) {
    for (unsigned j = k >> 1; j > 0; j >>= 1) {
      for (unsigned i = tid; i < npow2; i += 256) {
        unsigned ixj = i ^ j;
        if (ixj > i) {
          unsigned long long a = sk[i], b = sk[ixj];
          bool desc = ((i & k) == 0);
          if (desc ? (a < b) : (a > b)) { sk[i] = b; sk[ixj] = a; }
        }
      }
      __syncthreads();
    }
  }

  // prefetch candidate boxes into LDS (parallel gather, removes ~900cyc
  // serial global loads from the greedy scan)
  for (unsigned i = tid; i < n; i += 256) {
    unsigned r = 0xFFFFFFFFu - (unsigned)(sk[i] & 0xFFFFFFFFull);
    cbox[i] = boxes[r];
  }
  __syncthreads();

  // greedy scan: wave 0 only, kept boxes in lane registers (slots tid, tid+64)
  if (tid < 64) {
    int nk = 0;
    float ax1=0,ay1=0,ax2=0,ay2=0,aar=0;
    float bx1=0,by1=0,bx2=0,by2=0,bar=0;
    for (unsigned c = 0; c < n && nk < MAX_OUT; ++c) {
      unsigned long long key = sk[c];
      unsigned sbits = (unsigned)(key >> 32);
      if (sbits == 0u) break;
      float4 bb = cbox[c];
      float area = (bb.z - bb.x) * (bb.w - bb.y);
      bool s0 = false, s1 = false;
      if (tid < nk) {
        float xx1 = fmaxf(ax1, bb.x), yy1 = fmaxf(ay1, bb.y);
        float xx2 = fminf(ax2, bb.z), yy2 = fminf(ay2, bb.w);
        float inter = fmaxf(xx2 - xx1, 0.f) * fmaxf(yy2 - yy1, 0.f);
        float uni = aar + area - inter;
        s0 = (uni > 0.f) && (inter / uni > 0.5f);
      }
      if (tid + 64 < nk) {
        float xx1 = fmaxf(bx1, bb.x), yy1 = fmaxf(by1, bb.y);
        float xx2 = fminf(bx2, bb.z), yy2 = fminf(by2, bb.w);
        float inter = fmaxf(xx2 - xx1, 0.f) * fmaxf(yy2 - yy1, 0.f);
        float uni = bar + area - inter;
        s1 = (uni > 0.f) && (inter / uni > 0.5f);
      }
      if (!__any(s0 || s1)) {
        if (tid == nk)      { ax1=bb.x; ay1=bb.y; ax2=bb.z; ay2=bb.w; aar=area; }
        if (tid == nk - 64) { bx1=bb.x; by1=bb.y; bx2=bb.z; by2=bb.w; bar=area; }
        if (tid == 0) {
          unsigned r = 0xFFFFFFFFu - (unsigned)(key & 0xFFFFFFFFull);
          kbox[nk] = bb; kscore[nk] = __uint_as_float(sbits); krow[nk] = (int)r;
        }
        ++nk;
      }
    }
    if (tid == 0) knum = nk;
  }
  __syncthreads();

  // outputs: [0..99] conf, [100..499] boxes (100,4), [500..599] classes (float)
  if (tid < MAX_OUT) {
    float conf = 0.f; float4 bb = make_float4(0.f, 0.f, 0.f, 0.f); float cf = -1.f;
    if (tid < knum) { conf = kscore[tid]; bb = kbox[tid]; cf = (float)classes[krow[tid]]; }
    out[tid] = conf;
    ((float4*)(out + 100))[tid] = bb;
    out[500 + tid] = cf;
  }
}

// ---------------------------------------------------------------------------
extern "C" void kernel_launch(void* const* d_in, const int* in_sizes, int n_in,
                              void* d_out, int out_size, void* d_ws, size_t ws_size,
                              hipStream_t stream) {
  const float* x       = (const float*)d_in[0];
  const float* anchors = (const float*)d_in[1];
  float* out = (float*)d_out;
  char* ws = (char*)d_ws;

  float4*             boxes    = (float4*)(ws + WS_BOXES);
  float*              scores   = (float*)(ws + WS_SCORES);
  int*                classes  = (int*)(ws + WS_CLASSES);
  unsigned*           hist     = (unsigned*)(ws + WS_HIST);
  unsigned*           counters = (unsigned*)(ws + WS_COUNTERS);
  unsigned long long* keys     = (unsigned long long*)(ws + WS_KEYS);

  hipMemsetAsync(hist, 0, 65536 * sizeof(unsigned) + 64, stream);

  hipLaunchKernelGGL(decode_kernel, dim3(NROW / ROWS_PER_BLOCK), dim3(ROWS_PER_BLOCK),
                     0, stream, x, anchors, boxes, scores, classes, hist);
  hipLaunchKernelGGL(thresh_kernel, dim3(1), dim3(1024), 0, stream, hist, counters);
  hipLaunchKernelGGL(compact_kernel, dim3(NROW / 4 / 256), dim3(256),
                     0, stream, scores, counters, keys);
  hipLaunchKernelGGL(nms_kernel, dim3(1), dim3(256), 0, stream,
                     boxes, classes, keys, counters, out);
}

// Round 3
// 409.833 us; speedup vs baseline: 1.1923x; 1.0324x over previous
//
#include <hip/hip_runtime.h>
#include <hip/hip_bf16.h>

#define NROW 327680            // 256*256*5
#define NCLS 80
#define K_TARGET 1024u
#define CAP 2048u
#define MAX_OUT 100

// ---------------- workspace layout (bytes) ----------------
#define WS_BOXES    0           // float4[NROW]  5,242,880
#define WS_SCORES   5242880     // float [NROW]  1,310,720
#define WS_CLASSES  6553600     // int   [NROW]  1,310,720
#define WS_HIST     7864320     // uint  [65536]   262,144

typedef float f4v __attribute__((ext_vector_type(4)));
typedef f4v f4u __attribute__((aligned(4)));   // 4B-aligned float4 load

// ---------------------------------------------------------------------------
// Kernel 1: decode. One thread per row, row loaded straight into VGPRs.
// No LDS, no barriers -> occupancy limited only by VGPRs (~16-20 waves/CU),
// fixing R2's 3.7-waves/CU latency exposure. Math op-order identical to R2
// (absmax was 0.0): sequential argmax, sequential softmax sum, precise expf.
// ---------------------------------------------------------------------------
__global__ __launch_bounds__(256) void decode_kernel(
    const float* __restrict__ x, const float* __restrict__ anchors,
    float4* __restrict__ boxes, float* __restrict__ scores,
    int* __restrict__ classes, unsigned* __restrict__ hist) {
  const int r = blockIdx.x * 256 + threadIdx.x;
  const float* rowp = x + (size_t)r * 85;

  float v[85];
  #pragma unroll
  for (int c = 0; c < 21; ++c) {             // 21 x dwordx4 = elements 0..83
    f4v t = *(const f4u*)(rowp + 4 * c);
    v[4*c+0] = t.x; v[4*c+1] = t.y; v[4*c+2] = t.z; v[4*c+3] = t.w;
  }
  v[84] = rowp[84];

  // argmax of logits (first occurrence) == argmax of conf*softmax
  float m = v[5]; int am = 0;
  #pragma unroll
  for (int c = 1; c < NCLS; ++c) { float l = v[5 + c]; if (l > m) { m = l; am = c; } }
  // sequential fp32 softmax denominator (exact order as reference)
  float s = 0.f;
  #pragma unroll
  for (int c = 0; c < NCLS; ++c) s += expf(v[5 + c] - m);
  float conf = 1.f / (1.f + expf(-v[4]));
  float p = 1.f / s;                         // == fl(exp(0)/s) at the argmax
  float best = conf * p;
  float score; int cls;
  if (best > 0.01f) { score = best; cls = am; } else { score = 0.f; cls = 0; }

  const int a  = r % 5;
  const int hw = r / 5;
  const float wf = (float)(hw & 255);
  const float hf = (float)(hw >> 8);
  float sx = 1.f / (1.f + expf(-v[0]));
  float sy = 1.f / (1.f + expf(-v[1]));
  float xc = (sx + wf) / 256.f;
  float yc = (sy + hf) / 256.f;
  float bw = expf(v[2]) * anchors[2*a]     / 256.f;
  float bh = expf(v[3]) * anchors[2*a + 1] / 256.f;
  float hwd = bw / 2.f, hhd = bh / 2.f;

  boxes[r]   = make_float4(xc - hwd, yc - hhd, xc + hwd, yc + hhd);
  scores[r]  = score;
  classes[r] = cls;
  if (score > 0.f) atomicAdd(&hist[__float_as_uint(score) >> 16], 1u);
}

// ---------------------------------------------------------------------------
// Kernel 2 (fused): threshold + compact-to-LDS + bitonic sort + greedy NMS.
// Single block, 1024 threads. Removes 2 launch nodes and all global
// keys/counters round-trips vs R2.
// ---------------------------------------------------------------------------
__global__ __launch_bounds__(1024) void nms_fused(
    const float* __restrict__ scores, const float4* __restrict__ boxes,
    const int* __restrict__ classes, const unsigned* __restrict__ hist,
    float* __restrict__ out) {
  __shared__ unsigned bufA[1024], bufB[1024];
  __shared__ unsigned chunkbins[64];
  __shared__ int cstar;
  __shared__ unsigned Tsh, ncand;
  __shared__ unsigned long long sk[CAP];     // 16 KB
  __shared__ float4 cbox[CAP];               // 32 KB
  __shared__ float4 kbox[MAX_OUT];
  __shared__ float  kscore[MAX_OUT];
  __shared__ int    krow[MAX_OUT];
  __shared__ int    knum;
  const int t = threadIdx.x;
  if (t == 0) { cstar = -1; ncand = 0; knum = 0; }

  // ---- phase 1: threshold from 64K-bin histogram (suffix scan) ----
  unsigned ssum = 0;
  const uint4* h4 = (const uint4*)(hist + t * 64);
  #pragma unroll
  for (int i = 0; i < 16; ++i) { uint4 u = h4[i]; ssum += u.x + u.y + u.z + u.w; }
  bufA[t] = ssum;
  __syncthreads();
  unsigned* src = bufA; unsigned* dst = bufB;
  for (int d = 1; d < 1024; d <<= 1) {
    unsigned val = src[t] + ((t + d < 1024) ? src[t + d] : 0u);
    dst[t] = val;
    __syncthreads();
    unsigned* tmp = src; src = dst; dst = tmp;
  }
  if (src[t] >= K_TARGET && (t == 1023 || src[t + 1] < K_TARGET)) cstar = t;
  __syncthreads();
  int c = cstar;
  if (c >= 0 && t < 64) chunkbins[t] = hist[c * 64 + t];
  __syncthreads();
  if (t == 0) {
    unsigned T = 0;
    if (c >= 0) {
      unsigned cum = (c == 1023) ? 0u : src[c + 1];
      for (int b = 63; b >= 0; --b) {
        cum += chunkbins[b];
        if (cum >= K_TARGET) {
          T = (unsigned)(c * 64 + b);
          if (cum > CAP) T += 1;   // stricter bin; residual < K_TARGET <= CAP
          break;
        }
      }
    }
    Tsh = T;
  }
  __syncthreads();
  const unsigned T = Tsh;

  // ---- phase 2: compact candidates straight into LDS ----
  const float4* s4p = (const float4*)scores;
  for (int i = t; i < NROW / 4; i += 1024) {
    float4 s4 = s4p[i];
    float sv[4] = {s4.x, s4.y, s4.z, s4.w};
    #pragma unroll
    for (int k2 = 0; k2 < 4; ++k2) {
      float s = sv[k2];
      if (s <= 0.f) continue;
      unsigned bits = __float_as_uint(s);
      if ((bits >> 16) < T) continue;
      unsigned pos = atomicAdd(&ncand, 1u);
      if (pos < CAP)
        sk[pos] = ((unsigned long long)bits << 32) |
                  (unsigned long long)(0xFFFFFFFFu - (unsigned)(4 * i + k2));
    }
  }
  __syncthreads();
  unsigned n = ncand; if (n > CAP) n = CAP;
  unsigned npow2 = 2; while (npow2 < n) npow2 <<= 1;
  for (unsigned i = t; i < npow2; i += 1024) if (i >= n) sk[i] = 0ull;
  __syncthreads();

  // ---- phase 3: bitonic sort desc (key = score_bits<<32 | ~idx, stable) ----
  for (unsigned k = 2; k <= npow2; k <<= 1) {
    for (unsigned j = k >> 1; j > 0; j >>= 1) {
      for (unsigned i = t; i < npow2; i += 1024) {
        unsigned ixj = i ^ j;
        if (ixj > i) {
          unsigned long long a = sk[i], b = sk[ixj];
          bool desc = ((i & k) == 0);
          if (desc ? (a < b) : (a > b)) { sk[i] = b; sk[ixj] = a; }
        }
      }
      __syncthreads();
    }
  }

  // ---- phase 4: gather candidate boxes into LDS ----
  for (unsigned i = t; i < n; i += 1024) {
    unsigned r = 0xFFFFFFFFu - (unsigned)(sk[i] & 0xFFFFFFFFull);
    cbox[i] = boxes[r];
  }
  __syncthreads();

  // ---- phase 5: greedy scan, wave 0 only; kept boxes in lane registers ----
  if (t < 64) {
    int nk = 0;
    float ax1=0,ay1=0,ax2=0,ay2=0,aar=0;
    float bx1=0,by1=0,bx2=0,by2=0,bar=0;
    for (unsigned cc = 0; cc < n && nk < MAX_OUT; ++cc) {
      unsigned long long key = sk[cc];
      unsigned sbits = (unsigned)(key >> 32);
      if (sbits == 0u) break;
      float4 bb = cbox[cc];
      float area = (bb.z - bb.x) * (bb.w - bb.y);
      bool s0 = false, s1 = false;
      if (t < nk) {
        float xx1 = fmaxf(ax1, bb.x), yy1 = fmaxf(ay1, bb.y);
        float xx2 = fminf(ax2, bb.z), yy2 = fminf(ay2, bb.w);
        float inter = fmaxf(xx2 - xx1, 0.f) * fmaxf(yy2 - yy1, 0.f);
        float uni = aar + area - inter;
        s0 = (uni > 0.f) && (inter / uni > 0.5f);
      }
      if (t + 64 < nk) {
        float xx1 = fmaxf(bx1, bb.x), yy1 = fmaxf(by1, bb.y);
        float xx2 = fminf(bx2, bb.z), yy2 = fminf(by2, bb.w);
        float inter = fmaxf(xx2 - xx1, 0.f) * fmaxf(yy2 - yy1, 0.f);
        float uni = bar + area - inter;
        s1 = (uni > 0.f) && (inter / uni > 0.5f);
      }
      if (!__any(s0 || s1)) {
        if (t == nk)      { ax1=bb.x; ay1=bb.y; ax2=bb.z; ay2=bb.w; aar=area; }
        if (t == nk - 64) { bx1=bb.x; by1=bb.y; bx2=bb.z; by2=bb.w; bar=area; }
        if (t == 0) {
          unsigned r = 0xFFFFFFFFu - (unsigned)(key & 0xFFFFFFFFull);
          kbox[nk] = bb; kscore[nk] = __uint_as_float(sbits); krow[nk] = (int)r;
        }
        ++nk;
      }
    }
    if (t == 0) knum = nk;
  }
  __syncthreads();

  // ---- phase 6: outputs [0..99] conf, [100..499] boxes, [500..599] classes ----
  if (t < MAX_OUT) {
    float confv = 0.f; float4 bb = make_float4(0.f, 0.f, 0.f, 0.f); float cf = -1.f;
    if (t < knum) { confv = kscore[t]; bb = kbox[t]; cf = (float)classes[krow[t]]; }
    out[t] = confv;
    ((float4*)(out + 100))[t] = bb;
    out[500 + t] = cf;
  }
}

// ---------------------------------------------------------------------------
extern "C" void kernel_launch(void* const* d_in, const int* in_sizes, int n_in,
                              void* d_out, int out_size, void* d_ws, size_t ws_size,
                              hipStream_t stream) {
  const float* x       = (const float*)d_in[0];
  const float* anchors = (const float*)d_in[1];
  float* out = (float*)d_out;
  char* ws = (char*)d_ws;

  float4*   boxes   = (float4*)(ws + WS_BOXES);
  float*    scores  = (float*)(ws + WS_SCORES);
  int*      classes = (int*)(ws + WS_CLASSES);
  unsigned* hist    = (unsigned*)(ws + WS_HIST);

  hipMemsetAsync(hist, 0, 65536 * sizeof(unsigned), stream);

  hipLaunchKernelGGL(decode_kernel, dim3(NROW / 256), dim3(256),
                     0, stream, x, anchors, boxes, scores, classes, hist);
  hipLaunchKernelGGL(nms_fused, dim3(1), dim3(1024), 0, stream,
                     scores, boxes, classes, hist, out);
}

// Round 4
// 268.211 us; speedup vs baseline: 1.8218x; 1.5280x over previous
//
#include <hip/hip_runtime.h>
#include <hip/hip_bf16.h>

#define NROW 327680            // 256*256*5
#define NCLS 80
#define K_TARGET 1024u
#define CAP 2048u
#define MAX_OUT 100
#define NBIN 864               // score in (0.01,1): bits>>16 in [0x3C23, 0x3F80)
#define BIN0 0x3C23
#define HIST_BLOCKS 80

// ---------------- workspace layout (bytes) ----------------
#define WS_BOXES    0           // float4[NROW]  5,242,880
#define WS_SCORES   5242880     // float [NROW]  1,310,720
#define WS_CLASSES  6553600     // int   [NROW]  1,310,720
#define WS_HIST     7864320     // uint  [80*864]  276,480  (fully rewritten each call)

typedef __attribute__((address_space(1))) const unsigned int g_uint;
typedef __attribute__((address_space(3))) unsigned int lds_uint;

__device__ __forceinline__ void async_copy16(const float* g, float* l) {
  __builtin_amdgcn_global_load_lds((const g_uint*)g, (lds_uint*)l, 16, 0, 0);
}

// ---------------------------------------------------------------------------
// Kernel 1: decode, NO atomics. One wave per block, 64 rows staged to LDS via
// async 16B copies; no inter-wave barrier coupling (single-wave workgroup),
// ~7 blocks/CU -> ~150KB in flight per CU. Math op-order identical to R1-R3
// (absmax 0.0): sequential argmax, sequential softmax sum, precise expf.
// ---------------------------------------------------------------------------
__global__ __launch_bounds__(64) void decode_kernel(
    const float* __restrict__ x, const float* __restrict__ anchors,
    float4* __restrict__ boxes, float* __restrict__ scores,
    int* __restrict__ classes) {
  __shared__ float lds[64 * 85];           // 21,760 B, rows contiguous (no pad)
  const int t = threadIdx.x;
  const int row0 = blockIdx.x * 64;
  const float* gbase = x + (size_t)row0 * 85;

  // 64*85 floats = 1360 x 16B transfers: 21 full rounds + 16-lane tail
  #pragma unroll
  for (int i = 0; i < 21; ++i) {
    const int idx = i * 64 + t;
    async_copy16(gbase + idx * 4, lds + idx * 4);
  }
  if (t < 16) {
    const int idx = 1344 + t;
    async_copy16(gbase + idx * 4, lds + idx * 4);
  }
  __syncthreads();                          // single wave: vmcnt drain only

  const float* row = lds + t * 85;          // bank stride 21 mod 32: conflict-free
  const int r = row0 + t;

  float m = row[5]; int am = 0;
  for (int c = 1; c < NCLS; ++c) { float l = row[5 + c]; if (l > m) { m = l; am = c; } }
  float s = 0.f;
  for (int c = 0; c < NCLS; ++c) s += expf(row[5 + c] - m);
  float conf = 1.f / (1.f + expf(-row[4]));
  float p = 1.f / s;                        // == fl(exp(0)/s) at the argmax
  float best = conf * p;
  float score; int cls;
  if (best > 0.01f) { score = best; cls = am; } else { score = 0.f; cls = 0; }

  const int a  = r % 5;
  const int hw = r / 5;
  const float wf = (float)(hw & 255);
  const float hf = (float)(hw >> 8);
  float sx = 1.f / (1.f + expf(-row[0]));
  float sy = 1.f / (1.f + expf(-row[1]));
  float xc = (sx + wf) / 256.f;
  float yc = (sy + hf) / 256.f;
  float bw = expf(row[2]) * anchors[2*a]     / 256.f;
  float bh = expf(row[3]) * anchors[2*a + 1] / 256.f;
  float hwd = bw / 2.f, hhd = bh / 2.f;

  boxes[r]   = make_float4(xc - hwd, yc - hhd, xc + hwd, yc + hhd);
  scores[r]  = score;
  classes[r] = cls;
}

// ---------------------------------------------------------------------------
// Kernel 2: per-block LDS histogram -> part[block][bin]. ZERO global atomics.
// 80 blocks x 1024 threads x 1 float4 covers NROW exactly.
// ---------------------------------------------------------------------------
__global__ __launch_bounds__(1024) void hist_kernel(
    const float* __restrict__ scores, unsigned* __restrict__ part) {
  __shared__ unsigned h[NBIN];
  const int t = threadIdx.x;
  if (t < NBIN) h[t] = 0;
  __syncthreads();

  float4 s4 = ((const float4*)scores)[blockIdx.x * 1024 + t];
  float sv[4] = {s4.x, s4.y, s4.z, s4.w};
  #pragma unroll
  for (int k = 0; k < 4; ++k) {
    float s = sv[k];
    if (s > 0.f) {
      int idx = (int)(__float_as_uint(s) >> 16) - BIN0;   // >=0 since s>0.01
      if (idx > NBIN - 1) idx = NBIN - 1;
      atomicAdd(&h[idx], 1u);                              // LDS atomic only
    }
  }
  __syncthreads();
  if (t < NBIN) part[blockIdx.x * NBIN + t] = h[t];
}

// ---------------------------------------------------------------------------
// Kernel 3 (fused): reduce hist -> threshold -> compact -> sort -> greedy NMS
// ---------------------------------------------------------------------------
__global__ __launch_bounds__(1024) void nms_fused(
    const float* __restrict__ scores, const float4* __restrict__ boxes,
    const int* __restrict__ classes, const unsigned* __restrict__ part,
    float* __restrict__ out) {
  __shared__ unsigned bufA[1024], bufB[1024];
  __shared__ unsigned Tsh, ncand;
  __shared__ unsigned long long sk[CAP];     // 16 KB
  __shared__ float4 cbox[CAP];               // 32 KB
  __shared__ float4 kbox[MAX_OUT];
  __shared__ float  kscore[MAX_OUT];
  __shared__ int    krow[MAX_OUT];
  __shared__ int    knum;
  const int t = threadIdx.x;
  if (t == 0) { ncand = 0; knum = 0; }

  // ---- phase 1: column-reduce part[80][NBIN] (4-way unrolled, independent) ----
  unsigned colsum = 0;
  if (t < NBIN) {
    unsigned a0 = 0, a1 = 0, a2 = 0, a3 = 0;
    #pragma unroll
    for (int b = 0; b < HIST_BLOCKS; b += 4) {
      a0 += part[(b + 0) * NBIN + t];
      a1 += part[(b + 1) * NBIN + t];
      a2 += part[(b + 2) * NBIN + t];
      a3 += part[(b + 3) * NBIN + t];
    }
    colsum = a0 + a1 + a2 + a3;
  }
  bufA[t] = colsum;
  __syncthreads();

  // ---- suffix scan over 1024 bins (Hillis-Steele) ----
  unsigned* src = bufA; unsigned* dst = bufB;
  for (int d = 1; d < 1024; d <<= 1) {
    unsigned val = src[t] + ((t + d < 1024) ? src[t + d] : 0u);
    dst[t] = val;
    __syncthreads();
    unsigned* tmp = src; src = dst; dst = tmp;
  }
  // largest t with sfx >= K_TARGET; stricter bin if crossing cum > CAP
  if (src[t] >= K_TARGET && (t == 1023 || src[t + 1] < K_TARGET)) {
    unsigned T = (unsigned)t;
    if (src[t] > CAP) T += 1;   // residual sfx[t+1] < K_TARGET <= CAP
    Tsh = T;
  }
  if (t == 0 && src[0] < K_TARGET) Tsh = 0;  // fewer than K positives: take all
  __syncthreads();
  const unsigned T = Tsh;

  // ---- phase 2: compact to LDS keys (4-way unrolled independent loads) ----
  const float4* s4p = (const float4*)scores;
  for (int j = 0; j < 80; j += 4) {
    float4 q[4];
    q[0] = s4p[(j + 0) * 1024 + t];
    q[1] = s4p[(j + 1) * 1024 + t];
    q[2] = s4p[(j + 2) * 1024 + t];
    q[3] = s4p[(j + 3) * 1024 + t];
    #pragma unroll
    for (int u = 0; u < 4; ++u) {
      float sv[4] = {q[u].x, q[u].y, q[u].z, q[u].w};
      #pragma unroll
      for (int k = 0; k < 4; ++k) {
        float s = sv[k];
        if (s <= 0.f) continue;
        unsigned bits = __float_as_uint(s);
        int idx = (int)(bits >> 16) - BIN0;
        if (idx > NBIN - 1) idx = NBIN - 1;
        if ((unsigned)idx < T) continue;
        unsigned pos = atomicAdd(&ncand, 1u);
        unsigned r = (unsigned)(((j + u) * 1024 + t) * 4 + k);
        if (pos < CAP)
          sk[pos] = ((unsigned long long)bits << 32) |
                    (unsigned long long)(0xFFFFFFFFu - r);
      }
    }
  }
  __syncthreads();
  unsigned n = ncand; if (n > CAP) n = CAP;
  unsigned npow2 = 2; while (npow2 < n) npow2 <<= 1;
  for (unsigned i = t; i < npow2; i += 1024) if (i >= n) sk[i] = 0ull;
  __syncthreads();

  // ---- phase 3: bitonic sort desc (key = score_bits<<32 | ~idx, stable) ----
  for (unsigned k = 2; k <= npow2; k <<= 1) {
    for (unsigned j = k >> 1; j > 0; j >>= 1) {
      for (unsigned i = t; i < npow2; i += 1024) {
        unsigned ixj = i ^ j;
        if (ixj > i) {
          unsigned long long a = sk[i], b = sk[ixj];
          bool desc = ((i & k) == 0);
          if (desc ? (a < b) : (a > b)) { sk[i] = b; sk[ixj] = a; }
        }
      }
      __syncthreads();
    }
  }

  // ---- phase 4: gather candidate boxes into LDS ----
  for (unsigned i = t; i < n; i += 1024) {
    unsigned r = 0xFFFFFFFFu - (unsigned)(sk[i] & 0xFFFFFFFFull);
    cbox[i] = boxes[r];
  }
  __syncthreads();

  // ---- phase 5: greedy scan, wave 0 only; kept boxes in lane registers ----
  if (t < 64) {
    int nk = 0;
    float ax1=0,ay1=0,ax2=0,ay2=0,aar=0;
    float bx1=0,by1=0,bx2=0,by2=0,bar=0;
    for (unsigned cc = 0; cc < n && nk < MAX_OUT; ++cc) {
      unsigned long long key = sk[cc];
      unsigned sbits = (unsigned)(key >> 32);
      if (sbits == 0u) break;
      float4 bb = cbox[cc];
      float area = (bb.z - bb.x) * (bb.w - bb.y);
      bool s0 = false, s1 = false;
      if (t < nk) {
        float xx1 = fmaxf(ax1, bb.x), yy1 = fmaxf(ay1, bb.y);
        float xx2 = fminf(ax2, bb.z), yy2 = fminf(ay2, bb.w);
        float inter = fmaxf(xx2 - xx1, 0.f) * fmaxf(yy2 - yy1, 0.f);
        float uni = aar + area - inter;
        s0 = (uni > 0.f) && (inter / uni > 0.5f);
      }
      if (t + 64 < nk) {
        float xx1 = fmaxf(bx1, bb.x), yy1 = fmaxf(by1, bb.y);
        float xx2 = fminf(bx2, bb.z), yy2 = fminf(by2, bb.w);
        float inter = fmaxf(xx2 - xx1, 0.f) * fmaxf(yy2 - yy1, 0.f);
        float uni = bar + area - inter;
        s1 = (uni > 0.f) && (inter / uni > 0.5f);
      }
      if (!__any(s0 || s1)) {
        if (t == nk)      { ax1=bb.x; ay1=bb.y; ax2=bb.z; ay2=bb.w; aar=area; }
        if (t == nk - 64) { bx1=bb.x; by1=bb.y; bx2=bb.z; by2=bb.w; bar=area; }
        if (t == 0) {
          unsigned r = 0xFFFFFFFFu - (unsigned)(key & 0xFFFFFFFFull);
          kbox[nk] = bb; kscore[nk] = __uint_as_float(sbits); krow[nk] = (int)r;
        }
        ++nk;
      }
    }
    if (t == 0) knum = nk;
  }
  __syncthreads();

  // ---- phase 6: outputs [0..99] conf, [100..499] boxes, [500..599] classes ----
  if (t < MAX_OUT) {
    float confv = 0.f; float4 bb = make_float4(0.f, 0.f, 0.f, 0.f); float cf = -1.f;
    if (t < knum) { confv = kscore[t]; bb = kbox[t]; cf = (float)classes[krow[t]]; }
    out[t] = confv;
    ((float4*)(out + 100))[t] = bb;
    out[500 + t] = cf;
  }
}

// ---------------------------------------------------------------------------
extern "C" void kernel_launch(void* const* d_in, const int* in_sizes, int n_in,
                              void* d_out, int out_size, void* d_ws, size_t ws_size,
                              hipStream_t stream) {
  const float* x       = (const float*)d_in[0];
  const float* anchors = (const float*)d_in[1];
  float* out = (float*)d_out;
  char* ws = (char*)d_ws;

  float4*   boxes   = (float4*)(ws + WS_BOXES);
  float*    scores  = (float*)(ws + WS_SCORES);
  int*      classes = (int*)(ws + WS_CLASSES);
  unsigned* part    = (unsigned*)(ws + WS_HIST);

  hipLaunchKernelGGL(decode_kernel, dim3(NROW / 64), dim3(64),
                     0, stream, x, anchors, boxes, scores, classes);
  hipLaunchKernelGGL(hist_kernel, dim3(HIST_BLOCKS), dim3(1024),
                     0, stream, scores, part);
  hipLaunchKernelGGL(nms_fused, dim3(1), dim3(1024), 0, stream,
                     scores, boxes, classes, part, out);
}

// Round 5
// 249.321 us; speedup vs baseline: 1.9599x; 1.0758x over previous
//
#include <hip/hip_runtime.h>
#include <hip/hip_bf16.h>

#define NROW 327680            // 256*256*5
#define NCLS 80
#define K_TARGET 1024u
#define CAP 2048u
#define MAX_OUT 100
#define NBIN 864               // score in (0.01,1): bits>>16 in [0x3C23, 0x3F80)
#define BIN0 0x3C23

// ---------------- workspace layout (bytes) ----------------
#define WS_SCORES 0            // float[NROW]   1,310,720
#define WS_HIST   1310720      // uint[864]         3,456
#define WS_CNT    1314176      // uint[16]             64   (memset with hist)
#define WS_KEYS   1314240      // ull[CAP]         16,384

typedef __attribute__((address_space(1))) const unsigned int g_uint;
typedef __attribute__((address_space(3))) unsigned int lds_uint;

__device__ __forceinline__ void async_copy16(const float* g, float* l) {
  __builtin_amdgcn_global_load_lds((const g_uint*)g, (lds_uint*)l, 16, 0, 0);
}

// ---------------------------------------------------------------------------
// Kernel 1: scores only. Boxes/classes are recomputed later for the <=2048
// candidates / 100 keeps, so decode writes shrink 7.9MB -> 1.3MB and the
// argmax-index + box VALU work disappears from the hot 111MB streaming pass.
// Score op-order identical to R1-R4 (absmax 0.0): max, sequential expf sum,
// conf * (1/s).
// ---------------------------------------------------------------------------
__global__ __launch_bounds__(64) void decode_score(
    const float* __restrict__ x, float* __restrict__ scores) {
  __shared__ float lds[64 * 85];           // 21,760 B -> 7 blocks/CU
  const int t = threadIdx.x;
  const int row0 = blockIdx.x * 64;
  const float* gbase = x + (size_t)row0 * 85;

  #pragma unroll
  for (int i = 0; i < 21; ++i) {
    const int idx = i * 64 + t;
    async_copy16(gbase + idx * 4, lds + idx * 4);
  }
  if (t < 16) {
    const int idx = 1344 + t;
    async_copy16(gbase + idx * 4, lds + idx * 4);
  }
  __syncthreads();

  const float* row = lds + t * 85;         // stride 85 mod 32 = 21: conflict-free
  float m = row[5];
  for (int c = 1; c < NCLS; ++c) { float l = row[5 + c]; if (l > m) m = l; }
  float s = 0.f;
  for (int c = 0; c < NCLS; ++c) s += expf(row[5 + c] - m);
  float conf = 1.f / (1.f + expf(-row[4]));
  float p = 1.f / s;
  float best = conf * p;
  scores[row0 + t] = (best > 0.01f) ? best : 0.f;
}

// ---------------------------------------------------------------------------
// Kernel 2: per-block LDS histogram, merged via <=69k evenly-spread global
// atomics (80 per bin max — not R3's 321k hot-line ops).
// ---------------------------------------------------------------------------
__global__ __launch_bounds__(1024) void hist_kernel(
    const float* __restrict__ scores, unsigned* __restrict__ hist) {
  __shared__ unsigned h[NBIN];
  const int t = threadIdx.x;
  if (t < NBIN) h[t] = 0;
  __syncthreads();

  float4 s4 = ((const float4*)scores)[blockIdx.x * 1024 + t];
  float sv[4] = {s4.x, s4.y, s4.z, s4.w};
  #pragma unroll
  for (int k = 0; k < 4; ++k) {
    float s = sv[k];
    if (s > 0.f) {
      int idx = (int)(__float_as_uint(s) >> 16) - BIN0;
      if (idx > NBIN - 1) idx = NBIN - 1;
      atomicAdd(&h[idx], 1u);             // LDS atomic
    }
  }
  __syncthreads();
  if (t < NBIN && h[t]) atomicAdd(&hist[t], h[t]);
}

// ---------------------------------------------------------------------------
// Kernel 3: suffix-scan 864 bins -> threshold T (same semantics as R4).
// ---------------------------------------------------------------------------
__global__ __launch_bounds__(1024) void thresh_kernel(
    const unsigned* __restrict__ hist, unsigned* __restrict__ cnt) {
  __shared__ unsigned bufA[1024], bufB[1024];
  const int t = threadIdx.x;
  bufA[t] = (t < NBIN) ? hist[t] : 0u;
  __syncthreads();
  unsigned* src = bufA; unsigned* dst = bufB;
  for (int d = 1; d < 1024; d <<= 1) {
    unsigned val = src[t] + ((t + d < 1024) ? src[t + d] : 0u);
    dst[t] = val;
    __syncthreads();
    unsigned* tmp = src; src = dst; dst = tmp;
  }
  if (src[t] >= K_TARGET && (t == 1023 || src[t + 1] < K_TARGET)) {
    unsigned T = (unsigned)t;
    if (src[t] > CAP) T += 1;             // residual sfx[t+1] < K_TARGET <= CAP
    cnt[1] = T;
  }
  if (t == 0 && src[0] < K_TARGET) cnt[1] = 0;
}

// ---------------------------------------------------------------------------
// Kernel 4: device-wide compact. ONE global atomic per block (block-
// aggregated); key order is normalized later by the stable sort.
// ---------------------------------------------------------------------------
__global__ __launch_bounds__(256) void compact_kernel(
    const float* __restrict__ scores, unsigned* __restrict__ cnt,
    unsigned long long* __restrict__ keys) {
  __shared__ unsigned blocal, bbase;
  const int t = threadIdx.x;
  if (t == 0) blocal = 0;
  __syncthreads();

  const unsigned T = cnt[1];
  const int gi = blockIdx.x * 256 + t;
  float4 s4 = ((const float4*)scores)[gi];
  float sv[4] = {s4.x, s4.y, s4.z, s4.w};
  unsigned long long lk[4]; int nl = 0;
  #pragma unroll
  for (int k = 0; k < 4; ++k) {
    float s = sv[k];
    if (s <= 0.f) continue;
    unsigned bits = __float_as_uint(s);
    int idx = (int)(bits >> 16) - BIN0;
    if (idx > NBIN - 1) idx = NBIN - 1;
    if ((unsigned)idx < T) continue;
    unsigned r = (unsigned)(gi * 4 + k);
    lk[nl++] = ((unsigned long long)bits << 32) |
               (unsigned long long)(0xFFFFFFFFu - r);
  }
  unsigned lpos = nl ? atomicAdd(&blocal, (unsigned)nl) : 0u;
  __syncthreads();
  if (t == 0 && blocal) bbase = atomicAdd(&cnt[0], blocal);
  __syncthreads();
  if (nl) {
    unsigned base = bbase + lpos;
    for (int i = 0; i < nl; ++i)
      if (base + i < CAP) keys[base + i] = lk[i];
  }
}

// ---------------------------------------------------------------------------
// Kernel 5: sort + gather boxes from x + greedy NMS + per-kept argmax + out.
// Only the inherently serial ~30us remains single-block.
// ---------------------------------------------------------------------------
__global__ __launch_bounds__(1024) void final_kernel(
    const float* __restrict__ x, const float* __restrict__ anchors,
    const unsigned* __restrict__ cnt, const unsigned long long* __restrict__ keys,
    float* __restrict__ out) {
  __shared__ unsigned long long sk[CAP];   // 16 KB
  __shared__ float4 cbox[CAP];             // 32 KB
  __shared__ float4 kbox[MAX_OUT];
  __shared__ float  kscore[MAX_OUT];
  __shared__ int    krow[MAX_OUT];
  __shared__ int    knum;
  const int t = threadIdx.x;
  if (t == 0) knum = 0;

  unsigned n = cnt[0]; if (n > CAP) n = CAP;
  unsigned npow2 = 2; while (npow2 < n) npow2 <<= 1;
  for (unsigned i = t; i < npow2; i += 1024) sk[i] = (i < n) ? keys[i] : 0ull;
  __syncthreads();

  // bitonic sort desc (key = score_bits<<32 | ~idx -> exact argmax order)
  for (unsigned k = 2; k <= npow2; k <<= 1) {
    for (unsigned j = k >> 1; j > 0; j >>= 1) {
      for (unsigned i = t; i < npow2; i += 1024) {
        unsigned ixj = i ^ j;
        if (ixj > i) {
          unsigned long long a = sk[i], b = sk[ixj];
          bool desc = ((i & k) == 0);
          if (desc ? (a < b) : (a > b)) { sk[i] = b; sk[ixj] = a; }
        }
      }
      __syncthreads();
    }
  }

  // gather + decode boxes for candidates (expressions verbatim from R4 decode)
  for (unsigned i = t; i < n; i += 1024) {
    unsigned r = 0xFFFFFFFFu - (unsigned)(sk[i] & 0xFFFFFFFFull);
    const float* rp = x + (size_t)r * 85;
    float tx = rp[0], ty = rp[1], tw = rp[2], th = rp[3];
    const int a  = (int)(r % 5u);
    const int hw = (int)(r / 5u);
    const float wf = (float)(hw & 255);
    const float hf = (float)(hw >> 8);
    float sx = 1.f / (1.f + expf(-tx));
    float sy = 1.f / (1.f + expf(-ty));
    float xc = (sx + wf) / 256.f;
    float yc = (sy + hf) / 256.f;
    float bw = expf(tw) * anchors[2*a]     / 256.f;
    float bh = expf(th) * anchors[2*a + 1] / 256.f;
    float hwd = bw / 2.f, hhd = bh / 2.f;
    cbox[i] = make_float4(xc - hwd, yc - hhd, xc + hwd, yc + hhd);
  }
  __syncthreads();

  // greedy scan: wave 0 only, kept boxes in lane registers (slots t, t+64)
  if (t < 64) {
    int nk = 0;
    float ax1=0,ay1=0,ax2=0,ay2=0,aar=0;
    float bx1=0,by1=0,bx2=0,by2=0,bar=0;
    for (unsigned cc = 0; cc < n && nk < MAX_OUT; ++cc) {
      unsigned long long key = sk[cc];
      unsigned sbits = (unsigned)(key >> 32);
      if (sbits == 0u) break;
      float4 bb = cbox[cc];
      float area = (bb.z - bb.x) * (bb.w - bb.y);
      bool s0 = false, s1 = false;
      if (t < nk) {
        float xx1 = fmaxf(ax1, bb.x), yy1 = fmaxf(ay1, bb.y);
        float xx2 = fminf(ax2, bb.z), yy2 = fminf(ay2, bb.w);
        float inter = fmaxf(xx2 - xx1, 0.f) * fmaxf(yy2 - yy1, 0.f);
        float uni = aar + area - inter;
        s0 = (uni > 0.f) && (inter / uni > 0.5f);
      }
      if (t + 64 < nk) {
        float xx1 = fmaxf(bx1, bb.x), yy1 = fmaxf(by1, bb.y);
        float xx2 = fminf(bx2, bb.z), yy2 = fminf(by2, bb.w);
        float inter = fmaxf(xx2 - xx1, 0.f) * fmaxf(yy2 - yy1, 0.f);
        float uni = bar + area - inter;
        s1 = (uni > 0.f) && (inter / uni > 0.5f);
      }
      if (!__any(s0 || s1)) {
        if (t == nk)      { ax1=bb.x; ay1=bb.y; ax2=bb.z; ay2=bb.w; aar=area; }
        if (t == nk - 64) { bx1=bb.x; by1=bb.y; bx2=bb.z; by2=bb.w; bar=area; }
        if (t == 0) {
          unsigned r = 0xFFFFFFFFu - (unsigned)(key & 0xFFFFFFFFull);
          kbox[nk] = bb; kscore[nk] = __uint_as_float(sbits); krow[nk] = (int)r;
        }
        ++nk;
      }
    }
    if (t == 0) knum = nk;
  }
  __syncthreads();

  // epilogue: class argmax only for the kept rows (same first-max order)
  if (t < MAX_OUT) {
    float conf = 0.f; float4 bb = make_float4(0.f, 0.f, 0.f, 0.f); float cf = -1.f;
    if (t < knum) {
      conf = kscore[t]; bb = kbox[t];
      const float* rp = x + (size_t)krow[t] * 85;
      float m = rp[5]; int am = 0;
      for (int c = 1; c < NCLS; ++c) { float l = rp[5 + c]; if (l > m) { m = l; am = c; } }
      cf = (float)am;
    }
    out[t] = conf;
    ((float4*)(out + 100))[t] = bb;
    out[500 + t] = cf;
  }
}

// ---------------------------------------------------------------------------
extern "C" void kernel_launch(void* const* d_in, const int* in_sizes, int n_in,
                              void* d_out, int out_size, void* d_ws, size_t ws_size,
                              hipStream_t stream) {
  const float* x       = (const float*)d_in[0];
  const float* anchors = (const float*)d_in[1];
  float* out = (float*)d_out;
  char* ws = (char*)d_ws;

  float*              scores = (float*)(ws + WS_SCORES);
  unsigned*           hist   = (unsigned*)(ws + WS_HIST);
  unsigned*           cnt    = (unsigned*)(ws + WS_CNT);
  unsigned long long* keys   = (unsigned long long*)(ws + WS_KEYS);

  hipMemsetAsync(hist, 0, NBIN * sizeof(unsigned) + 64, stream);  // hist + cnt

  hipLaunchKernelGGL(decode_score, dim3(NROW / 64), dim3(64),
                     0, stream, x, scores);
  hipLaunchKernelGGL(hist_kernel, dim3(NROW / 4096), dim3(1024),
                     0, stream, scores, hist);
  hipLaunchKernelGGL(thresh_kernel, dim3(1), dim3(1024), 0, stream, hist, cnt);
  hipLaunchKernelGGL(compact_kernel, dim3(NROW / 1024), dim3(256),
                     0, stream, scores, cnt, keys);
  hipLaunchKernelGGL(final_kernel, dim3(1), dim3(1024), 0, stream,
                     x, anchors, cnt, keys, out);
}

// Round 6
// 237.775 us; speedup vs baseline: 2.0550x; 1.0486x over previous
//
#include <hip/hip_runtime.h>
#include <hip/hip_bf16.h>

#define NROW 327680            // 256*256*5
#define NCLS 80
#define K_TARGET 1024u
#define CAP 2048u
#define MAX_OUT 100
#define NBIN 864               // score in (0.01,1): bits>>16 in [0x3C23, 0x3F80)
#define BIN0 0x3C23
#define HIST_BLOCKS 80

// ---------------- workspace layout (bytes) ----------------
#define WS_SCORES 0            // float[NROW]     1,310,720
#define WS_PART   1310720      // uint[80*864]      276,480 (fully rewritten)
#define WS_CNT    1587200      // uint[16]               64 (written by thresh)
#define WS_KEYS   1587264      // ull[CAP]           16,384

typedef float f4v __attribute__((ext_vector_type(4)));
typedef f4v f4u __attribute__((aligned(4)));   // 4B-aligned float4 load

// ---------------------------------------------------------------------------
// Kernel 1: scores only, row resident in VGPRs. __launch_bounds__(256,1)
// raises the VGPR budget to ~512 so the compiler does NOT rematerialize the
// 80-float logit array (R3's VGPR_Count=48 = remat signature). Score op-order
// identical to R1-R5 (absmax 0.0): sequential max, sequential expf sum,
// conf * (1/s).
// ---------------------------------------------------------------------------
__global__ __launch_bounds__(256, 1) void decode_score(
    const float* __restrict__ x, float* __restrict__ scores) {
  const int r = blockIdx.x * 256 + threadIdx.x;
  const float* rp = x + (size_t)r * 85;

  float conf_l = rp[4];
  float cl[80];
  #pragma unroll
  for (int c = 0; c < 20; ++c) {           // floats 5..84 = exactly 20 x vec4
    f4v t4 = *(const f4u*)(rp + 5 + 4 * c);
    cl[4*c+0] = t4.x; cl[4*c+1] = t4.y; cl[4*c+2] = t4.z; cl[4*c+3] = t4.w;
  }

  float m = cl[0];
  #pragma unroll
  for (int c = 1; c < NCLS; ++c) { float l = cl[c]; if (l > m) m = l; }
  float s = 0.f;
  #pragma unroll
  for (int c = 0; c < NCLS; ++c) s += expf(cl[c] - m);
  float conf = 1.f / (1.f + expf(-conf_l));
  float best = conf * (1.f / s);
  scores[r] = (best > 0.01f) ? best : 0.f;
}

// ---------------------------------------------------------------------------
// Kernel 2: per-block LDS histogram -> part[block][bin], non-atomic global
// writes (no memset needed, zero global atomics).
// ---------------------------------------------------------------------------
__global__ __launch_bounds__(1024) void hist_kernel(
    const float* __restrict__ scores, unsigned* __restrict__ part) {
  __shared__ unsigned h[NBIN];
  const int t = threadIdx.x;
  if (t < NBIN) h[t] = 0;
  __syncthreads();

  float4 s4 = ((const float4*)scores)[blockIdx.x * 1024 + t];
  float sv[4] = {s4.x, s4.y, s4.z, s4.w};
  #pragma unroll
  for (int k = 0; k < 4; ++k) {
    float s = sv[k];
    if (s > 0.f) {
      int idx = (int)(__float_as_uint(s) >> 16) - BIN0;
      if (idx > NBIN - 1) idx = NBIN - 1;
      atomicAdd(&h[idx], 1u);             // LDS atomic only
    }
  }
  __syncthreads();
  if (t < NBIN) part[blockIdx.x * NBIN + t] = h[t];
}

// ---------------------------------------------------------------------------
// Kernel 3: reduce part + suffix-scan -> threshold T; also zero-init cnt[0].
// ---------------------------------------------------------------------------
__global__ __launch_bounds__(1024) void thresh_kernel(
    const unsigned* __restrict__ part, unsigned* __restrict__ cnt) {
  __shared__ unsigned bufA[1024], bufB[1024];
  const int t = threadIdx.x;

  unsigned colsum = 0;
  if (t < NBIN) {
    unsigned a0 = 0, a1 = 0, a2 = 0, a3 = 0;
    #pragma unroll
    for (int b = 0; b < HIST_BLOCKS; b += 4) {
      a0 += part[(b + 0) * NBIN + t];
      a1 += part[(b + 1) * NBIN + t];
      a2 += part[(b + 2) * NBIN + t];
      a3 += part[(b + 3) * NBIN + t];
    }
    colsum = a0 + a1 + a2 + a3;
  }
  bufA[t] = colsum;
  __syncthreads();

  unsigned* src = bufA; unsigned* dst = bufB;
  for (int d = 1; d < 1024; d <<= 1) {
    unsigned val = src[t] + ((t + d < 1024) ? src[t + d] : 0u);
    dst[t] = val;
    __syncthreads();
    unsigned* tmp = src; src = dst; dst = tmp;
  }
  if (src[t] >= K_TARGET && (t == 1023 || src[t + 1] < K_TARGET)) {
    unsigned T = (unsigned)t;
    if (src[t] > CAP) T += 1;             // residual sfx[t+1] < K_TARGET <= CAP
    cnt[1] = T;
  }
  if (t == 0) {
    if (src[0] < K_TARGET) cnt[1] = 0;    // fewer than K positives: take all
    cnt[0] = 0;
  }
}

// ---------------------------------------------------------------------------
// Kernel 4: device-wide compact; one global atomic per block. Cross-block
// key order is nondeterministic but the full sort restores a total order
// (keys unique), and n <= CAP always (thresh bump rule) -> deterministic.
// ---------------------------------------------------------------------------
__global__ __launch_bounds__(256) void compact_kernel(
    const float* __restrict__ scores, unsigned* __restrict__ cnt,
    unsigned long long* __restrict__ keys) {
  __shared__ unsigned blocal, bbase;
  const int t = threadIdx.x;
  if (t == 0) blocal = 0;
  __syncthreads();

  const unsigned T = cnt[1];
  const int gi = blockIdx.x * 256 + t;
  float4 s4 = ((const float4*)scores)[gi];
  float sv[4] = {s4.x, s4.y, s4.z, s4.w};
  unsigned long long lk[4]; int nl = 0;
  #pragma unroll
  for (int k = 0; k < 4; ++k) {
    float s = sv[k];
    if (s <= 0.f) continue;
    unsigned bits = __float_as_uint(s);
    int idx = (int)(bits >> 16) - BIN0;
    if (idx > NBIN - 1) idx = NBIN - 1;
    if ((unsigned)idx < T) continue;
    unsigned r = (unsigned)(gi * 4 + k);
    lk[nl++] = ((unsigned long long)bits << 32) |
               (unsigned long long)(0xFFFFFFFFu - r);
  }
  unsigned lpos = nl ? atomicAdd(&blocal, (unsigned)nl) : 0u;
  __syncthreads();
  if (t == 0 && blocal) bbase = atomicAdd(&cnt[0], blocal);
  __syncthreads();
  if (nl) {
    unsigned base = bbase + lpos;
    for (int i = 0; i < nl; ++i)
      if (base + i < CAP) keys[base + i] = lk[i];
  }
}

// ---------------------------------------------------------------------------
// Kernel 5: sort + gather/decode candidate boxes + greedy NMS + parallel
// per-kept class argmax + output.
// ---------------------------------------------------------------------------
__global__ __launch_bounds__(1024) void final_kernel(
    const float* __restrict__ x, const float* __restrict__ anchors,
    const unsigned* __restrict__ cnt, const unsigned long long* __restrict__ keys,
    float* __restrict__ out) {
  __shared__ unsigned long long sk[CAP];   // 16 KB
  __shared__ float4 cbox[CAP];             // 32 KB
  __shared__ float4 kbox[MAX_OUT];
  __shared__ float  kscore[MAX_OUT];
  __shared__ int    krow[MAX_OUT];
  __shared__ int    kcls[MAX_OUT];
  __shared__ int    knum;
  const int t = threadIdx.x;
  if (t == 0) knum = 0;

  unsigned n = cnt[0]; if (n > CAP) n = CAP;
  unsigned npow2 = 2; while (npow2 < n) npow2 <<= 1;
  for (unsigned i = t; i < npow2; i += 1024) sk[i] = (i < n) ? keys[i] : 0ull;
  __syncthreads();

  // bitonic sort desc, all-threads-busy pair indexing (npow2/2 pairs/step)
  for (unsigned k = 2; k <= npow2; k <<= 1) {
    for (unsigned j = k >> 1; j > 0; j >>= 1) {
      for (unsigned p = t; p < (npow2 >> 1); p += 1024) {
        unsigned i = ((p & ~(j - 1u)) << 1) | (p & (j - 1u));
        unsigned ixj = i | j;
        unsigned long long a = sk[i], b = sk[ixj];
        bool desc = ((i & k) == 0);
        if (desc ? (a < b) : (a > b)) { sk[i] = b; sk[ixj] = a; }
      }
      __syncthreads();
    }
  }

  // gather + decode candidate boxes (expressions verbatim from prior rounds)
  for (unsigned i = t; i < n; i += 1024) {
    unsigned r = 0xFFFFFFFFu - (unsigned)(sk[i] & 0xFFFFFFFFull);
    const float* rp = x + (size_t)r * 85;
    float tx = rp[0], ty = rp[1], tw = rp[2], th = rp[3];
    const int a  = (int)(r % 5u);
    const int hw = (int)(r / 5u);
    const float wf = (float)(hw & 255);
    const float hf = (float)(hw >> 8);
    float sx = 1.f / (1.f + expf(-tx));
    float sy = 1.f / (1.f + expf(-ty));
    float xc = (sx + wf) / 256.f;
    float yc = (sy + hf) / 256.f;
    float bw = expf(tw) * anchors[2*a]     / 256.f;
    float bh = expf(th) * anchors[2*a + 1] / 256.f;
    float hwd = bw / 2.f, hhd = bh / 2.f;
    cbox[i] = make_float4(xc - hwd, yc - hhd, xc + hwd, yc + hhd);
  }
  __syncthreads();

  // greedy scan: wave 0, software-pipelined (prefetch next key+box)
  if (t < 64) {
    int nk = 0;
    float ax1=0,ay1=0,ax2=0,ay2=0,aar=0;
    float bx1=0,by1=0,bx2=0,by2=0,bar=0;
    unsigned long long key = (n > 0) ? sk[0] : 0ull;
    float4 bb = (n > 0) ? cbox[0] : make_float4(0,0,0,0);
    for (unsigned cc = 0; cc < n && nk < MAX_OUT; ++cc) {
      unsigned long long key_n = (cc + 1 < n) ? sk[cc + 1] : 0ull;
      float4 bb_n = (cc + 1 < n) ? cbox[cc + 1] : make_float4(0,0,0,0);
      unsigned sbits = (unsigned)(key >> 32);
      if (sbits == 0u) break;
      float area = (bb.z - bb.x) * (bb.w - bb.y);
      bool s0 = false, s1 = false;
      if (t < nk) {
        float xx1 = fmaxf(ax1, bb.x), yy1 = fmaxf(ay1, bb.y);
        float xx2 = fminf(ax2, bb.z), yy2 = fminf(ay2, bb.w);
        float inter = fmaxf(xx2 - xx1, 0.f) * fmaxf(yy2 - yy1, 0.f);
        float uni = aar + area - inter;
        s0 = (uni > 0.f) && (inter / uni > 0.5f);
      }
      if (t + 64 < nk) {
        float xx1 = fmaxf(bx1, bb.x), yy1 = fmaxf(by1, bb.y);
        float xx2 = fminf(bx2, bb.z), yy2 = fminf(by2, bb.w);
        float inter = fmaxf(xx2 - xx1, 0.f) * fmaxf(yy2 - yy1, 0.f);
        float uni = bar + area - inter;
        s1 = (uni > 0.f) && (inter / uni > 0.5f);
      }
      if (!__any(s0 || s1)) {
        if (t == nk)      { ax1=bb.x; ay1=bb.y; ax2=bb.z; ay2=bb.w; aar=area; }
        if (t == nk - 64) { bx1=bb.x; by1=bb.y; bx2=bb.z; by2=bb.w; bar=area; }
        if (t == 0) {
          unsigned r = 0xFFFFFFFFu - (unsigned)(key & 0xFFFFFFFFull);
          kbox[nk] = bb; kscore[nk] = __uint_as_float(sbits); krow[nk] = (int)r;
        }
        ++nk;
      }
      key = key_n; bb = bb_n;
    }
    if (t == 0) knum = nk;
  }
  __syncthreads();

  // wave-parallel class argmax: one wave per kept row; packed
  // (monotone-float-bits, ~class) max == sequential first-occurrence argmax
  {
    const int wv = t >> 6, lane = t & 63;
    for (int kidx = wv; kidx < knum; kidx += 16) {
      const float* rp = x + (size_t)krow[kidx] * 85;
      float l0 = rp[5 + lane];
      unsigned b0 = __float_as_uint(l0);
      b0 = (b0 & 0x80000000u) ? ~b0 : (b0 | 0x80000000u);
      unsigned long long kv =
          ((unsigned long long)b0 << 32) | (unsigned long long)(0xFFFFFFFFu - lane);
      if (lane < 16) {
        float l1 = rp[5 + 64 + lane];
        unsigned b1 = __float_as_uint(l1);
        b1 = (b1 & 0x80000000u) ? ~b1 : (b1 | 0x80000000u);
        unsigned long long kv1 =
            ((unsigned long long)b1 << 32) |
            (unsigned long long)(0xFFFFFFFFu - (64 + lane));
        if (kv1 > kv) kv = kv1;
      }
      #pragma unroll
      for (int d = 32; d >= 1; d >>= 1) {
        unsigned long long o = __shfl_xor((long long)kv, d, 64);
        if (o > kv) kv = o;
      }
      if (lane == 0)
        kcls[kidx] = (int)(0xFFFFFFFFu - (unsigned)(kv & 0xFFFFFFFFull));
    }
  }
  __syncthreads();

  // outputs: [0..99] conf, [100..499] boxes (100,4), [500..599] classes
  if (t < MAX_OUT) {
    float conf = 0.f; float4 bb = make_float4(0.f, 0.f, 0.f, 0.f); float cf = -1.f;
    if (t < knum) { conf = kscore[t]; bb = kbox[t]; cf = (float)kcls[t]; }
    out[t] = conf;
    ((float4*)(out + 100))[t] = bb;
    out[500 + t] = cf;
  }
}

// ---------------------------------------------------------------------------
extern "C" void kernel_launch(void* const* d_in, const int* in_sizes, int n_in,
                              void* d_out, int out_size, void* d_ws, size_t ws_size,
                              hipStream_t stream) {
  const float* x       = (const float*)d_in[0];
  const float* anchors = (const float*)d_in[1];
  float* out = (float*)d_out;
  char* ws = (char*)d_ws;

  float*              scores = (float*)(ws + WS_SCORES);
  unsigned*           part   = (unsigned*)(ws + WS_PART);
  unsigned*           cnt    = (unsigned*)(ws + WS_CNT);
  unsigned long long* keys   = (unsigned long long*)(ws + WS_KEYS);

  hipLaunchKernelGGL(decode_score, dim3(NROW / 256), dim3(256),
                     0, stream, x, scores);
  hipLaunchKernelGGL(hist_kernel, dim3(HIST_BLOCKS), dim3(1024),
                     0, stream, scores, part);
  hipLaunchKernelGGL(thresh_kernel, dim3(1), dim3(1024), 0, stream, part, cnt);
  hipLaunchKernelGGL(compact_kernel, dim3(NROW / 1024), dim3(256),
                     0, stream, scores, cnt, keys);
  hipLaunchKernelGGL(final_kernel, dim3(1), dim3(1024), 0, stream,
                     x, anchors, cnt, keys, out);
}

// Round 7
// 236.130 us; speedup vs baseline: 2.0693x; 1.0070x over previous
//
#include <hip/hip_runtime.h>
#include <hip/hip_bf16.h>

#define NROW 327680            // 256*256*5
#define NCLS 80
#define K_TARGET 1024u
#define CAP 2048u              // == MAXN
#define MAXN 2048
#define MAX_OUT 100
#define NBIN 864               // score in (0.01,1): bits>>16 in [0x3C23, 0x3F80)
#define BIN0 0x3C23
#define HIST_BLOCKS 80
#define ADJW 32                // 2048 bits = 32 ull per adjacency row
#define ADJC_ROWS 128          // adjacency rows cached in LDS for the greedy scan

// ---------------- workspace layout (bytes) ----------------
#define WS_SCORES 0            // float[NROW]          1,310,720
#define WS_PART   1310720      // uint[80*864]           276,480
#define WS_CNT    1587200      // uint[16]                    64
#define WS_KEYS   1587264      // ull[MAXN]               16,384
#define WS_SORT   1603648      // ull[MAXN]               16,384
#define WS_CBOX   1620032      // float4[MAXN]            32,768
#define WS_ADJ    1652800      // ull[MAXN*ADJW]         524,288

typedef float f4v __attribute__((ext_vector_type(4)));
typedef f4v f4u __attribute__((aligned(4)));   // 4B-aligned float4 load
typedef unsigned long long ull;

// ---------------------------------------------------------------------------
// Kernel 1: scores only, row resident in VGPRs (unchanged from R6; its
// counters will surface now that final_kernel shrinks). Score op-order
// identical to R1-R6 (absmax 0.0).
// ---------------------------------------------------------------------------
__global__ __launch_bounds__(256, 1) void decode_score(
    const float* __restrict__ x, float* __restrict__ scores) {
  const int r = blockIdx.x * 256 + threadIdx.x;
  const float* rp = x + (size_t)r * 85;

  float conf_l = rp[4];
  float cl[80];
  #pragma unroll
  for (int c = 0; c < 20; ++c) {           // floats 5..84 = exactly 20 x vec4
    f4v t4 = *(const f4u*)(rp + 5 + 4 * c);
    cl[4*c+0] = t4.x; cl[4*c+1] = t4.y; cl[4*c+2] = t4.z; cl[4*c+3] = t4.w;
  }

  float m = cl[0];
  #pragma unroll
  for (int c = 1; c < NCLS; ++c) { float l = cl[c]; if (l > m) m = l; }
  float s = 0.f;
  #pragma unroll
  for (int c = 0; c < NCLS; ++c) s += expf(cl[c] - m);
  float conf = 1.f / (1.f + expf(-conf_l));
  float best = conf * (1.f / s);
  scores[r] = (best > 0.01f) ? best : 0.f;
}

// ---------------------------------------------------------------------------
// Kernel 2: per-block LDS histogram -> part[block][bin] (non-atomic global).
// ---------------------------------------------------------------------------
__global__ __launch_bounds__(1024) void hist_kernel(
    const float* __restrict__ scores, unsigned* __restrict__ part) {
  __shared__ unsigned h[NBIN];
  const int t = threadIdx.x;
  if (t < NBIN) h[t] = 0;
  __syncthreads();

  float4 s4 = ((const float4*)scores)[blockIdx.x * 1024 + t];
  float sv[4] = {s4.x, s4.y, s4.z, s4.w};
  #pragma unroll
  for (int k = 0; k < 4; ++k) {
    float s = sv[k];
    if (s > 0.f) {
      int idx = (int)(__float_as_uint(s) >> 16) - BIN0;
      if (idx > NBIN - 1) idx = NBIN - 1;
      atomicAdd(&h[idx], 1u);             // LDS atomic only
    }
  }
  __syncthreads();
  if (t < NBIN) part[blockIdx.x * NBIN + t] = h[t];
}

// ---------------------------------------------------------------------------
// Kernel 3: reduce part + suffix-scan -> threshold T (bit-identical semantics
// to R4-R6); zero-init cnt[0].
// ---------------------------------------------------------------------------
__global__ __launch_bounds__(1024) void thresh_kernel(
    const unsigned* __restrict__ part, unsigned* __restrict__ cnt) {
  __shared__ unsigned bufA[1024], bufB[1024];
  const int t = threadIdx.x;

  unsigned colsum = 0;
  if (t < NBIN) {
    unsigned a0 = 0, a1 = 0, a2 = 0, a3 = 0;
    #pragma unroll
    for (int b = 0; b < HIST_BLOCKS; b += 4) {
      a0 += part[(b + 0) * NBIN + t];
      a1 += part[(b + 1) * NBIN + t];
      a2 += part[(b + 2) * NBIN + t];
      a3 += part[(b + 3) * NBIN + t];
    }
    colsum = a0 + a1 + a2 + a3;
  }
  bufA[t] = colsum;
  __syncthreads();

  unsigned* src = bufA; unsigned* dst = bufB;
  for (int d = 1; d < 1024; d <<= 1) {
    unsigned val = src[t] + ((t + d < 1024) ? src[t + d] : 0u);
    dst[t] = val;
    __syncthreads();
    unsigned* tmp = src; src = dst; dst = tmp;
  }
  if (src[t] >= K_TARGET && (t == 1023 || src[t + 1] < K_TARGET)) {
    unsigned T = (unsigned)t;
    if (src[t] > CAP) T += 1;             // residual sfx[t+1] < K_TARGET <= CAP
    cnt[1] = T;
  }
  if (t == 0) {
    if (src[0] < K_TARGET) cnt[1] = 0;    // fewer than K positives: take all
    cnt[0] = 0;
  }
}

// ---------------------------------------------------------------------------
// Kernel 4: device-wide compact; one global atomic per block. n <= CAP
// guaranteed by the thresh bump rule; order normalized by the rank sort.
// ---------------------------------------------------------------------------
__global__ __launch_bounds__(256) void compact_kernel(
    const float* __restrict__ scores, unsigned* __restrict__ cnt,
    ull* __restrict__ keys) {
  __shared__ unsigned blocal, bbase;
  const int t = threadIdx.x;
  if (t == 0) blocal = 0;
  __syncthreads();

  const unsigned T = cnt[1];
  const int gi = blockIdx.x * 256 + t;
  float4 s4 = ((const float4*)scores)[gi];
  float sv[4] = {s4.x, s4.y, s4.z, s4.w};
  ull lk[4]; int nl = 0;
  #pragma unroll
  for (int k = 0; k < 4; ++k) {
    float s = sv[k];
    if (s <= 0.f) continue;
    unsigned bits = __float_as_uint(s);
    int idx = (int)(bits >> 16) - BIN0;
    if (idx > NBIN - 1) idx = NBIN - 1;
    if ((unsigned)idx < T) continue;
    unsigned r = (unsigned)(gi * 4 + k);
    lk[nl++] = ((ull)bits << 32) | (ull)(0xFFFFFFFFu - r);
  }
  unsigned lpos = nl ? atomicAdd(&blocal, (unsigned)nl) : 0u;
  __syncthreads();
  if (t == 0 && blocal) bbase = atomicAdd(&cnt[0], blocal);
  __syncthreads();
  if (nl) {
    unsigned base = bbase + lpos;
    for (int i = 0; i < nl; ++i)
      if (base + i < CAP) keys[base + i] = lk[i];
  }
}

// ---------------------------------------------------------------------------
// Kernel 5: rank-scatter sort (device-wide, replaces 1-block bitonic).
// rank_i = #{j : key_j > key_i}; keys unique -> exact permutation, identical
// order to the bitonic desc sort. Also decodes candidate boxes (exact
// reference expressions) into cboxg[rank].
// ---------------------------------------------------------------------------
__global__ __launch_bounds__(64) void rank_kernel(
    const float* __restrict__ x, const float* __restrict__ anchors,
    const unsigned* __restrict__ cnt, const ull* __restrict__ keys,
    ull* __restrict__ sorted, float4* __restrict__ cboxg) {
  __shared__ ull lk[MAXN];
  unsigned n = cnt[0]; if (n > CAP) n = CAP;
  const int t = threadIdx.x;
  for (unsigned i = t; i < n; i += 64) lk[i] = keys[i];
  __syncthreads();

  const unsigned i = blockIdx.x * 64 + t;
  if (i >= n) return;
  const ull ki = lk[i];
  unsigned rank = 0;
  #pragma unroll 4
  for (unsigned j = 0; j < n; ++j) rank += (lk[j] > ki) ? 1u : 0u;

  sorted[rank] = ki;

  unsigned r = 0xFFFFFFFFu - (unsigned)(ki & 0xFFFFFFFFull);
  const float* rp = x + (size_t)r * 85;
  float tx = rp[0], ty = rp[1], tw = rp[2], th = rp[3];
  const int a  = (int)(r % 5u);
  const int hw = (int)(r / 5u);
  const float wf = (float)(hw & 255);
  const float hf = (float)(hw >> 8);
  float sx = 1.f / (1.f + expf(-tx));
  float sy = 1.f / (1.f + expf(-ty));
  float xc = (sx + wf) / 256.f;
  float yc = (sy + hf) / 256.f;
  float bw = expf(tw) * anchors[2*a]     / 256.f;
  float bh = expf(th) * anchors[2*a + 1] / 256.f;
  float hwd = bw / 2.f, hhd = bh / 2.f;
  cboxg[rank] = make_float4(xc - hwd, yc - hhd, xc + hwd, yc + hhd);
}

// ---------------------------------------------------------------------------
// Kernel 6: adjacency bitmap, device-wide. adj[i] bit j = IoU(i,j) > 0.5,
// using the reference's exact division-based IoU expression.
// ---------------------------------------------------------------------------
__global__ __launch_bounds__(256) void adj_kernel(
    const unsigned* __restrict__ cnt, const float4* __restrict__ cboxg,
    ull* __restrict__ adj) {
  unsigned n = cnt[0]; if (n > CAP) n = CAP;
  const unsigned i = blockIdx.x;
  if (i >= n) return;
  const float4 bi = cboxg[i];
  const float areai = (bi.z - bi.x) * (bi.w - bi.y);
  const int t = threadIdx.x, wid = t >> 6, lane = t & 63;

  #pragma unroll
  for (int pass = 0; pass < 8; ++pass) {
    unsigned j = (unsigned)(pass * 256 + t);
    bool sup = false;
    if (j < n) {
      float4 bj = cboxg[j];
      float xx1 = fmaxf(bi.x, bj.x), yy1 = fmaxf(bi.y, bj.y);
      float xx2 = fminf(bi.z, bj.z), yy2 = fminf(bi.w, bj.w);
      float inter = fmaxf(xx2 - xx1, 0.f) * fmaxf(yy2 - yy1, 0.f);
      float areaj = (bj.z - bj.x) * (bj.w - bj.y);
      float uni = areai + areaj - inter;
      float iou = (uni > 0.f) ? (inter / uni) : 0.f;
      sup = iou > 0.5f;
    }
    ull m = __ballot(sup);
    if (lane == 0) adj[(size_t)i * ADJW + pass * 4 + wid] = m;
  }
}

// ---------------------------------------------------------------------------
// Kernel 7: greedy NMS as a bitmask scan (stateless per-lane: 1 ull mask
// word/lane — nothing for the compiler to spill) + class argmax + output.
// ---------------------------------------------------------------------------
__global__ __launch_bounds__(1024) void final_kernel(
    const float* __restrict__ x, const unsigned* __restrict__ cnt,
    const ull* __restrict__ sorted, const float4* __restrict__ cboxg,
    const ull* __restrict__ adjg, float* __restrict__ out) {
  __shared__ ull sk[MAXN];                  // 16 KB
  __shared__ ull adjc[ADJC_ROWS * ADJW];    // 32 KB (rows 0..127 cached)
  __shared__ int keptcc[MAX_OUT];
  __shared__ int kcls[MAX_OUT];
  __shared__ int knum;
  const int t = threadIdx.x;
  if (t == 0) knum = 0;

  unsigned n = cnt[0]; if (n > CAP) n = CAP;
  for (unsigned i = t; i < n; i += 1024) sk[i] = sorted[i];
  const unsigned ncache = (n < ADJC_ROWS ? n : ADJC_ROWS) * ADJW;
  for (unsigned i = t; i < ncache; i += 1024) adjc[i] = adjg[i];
  __syncthreads();

  // ---- greedy bitmask scan: wave 0; lane l (l<32) owns mask word l ----
  if (t < 64) {
    const int lane = t;
    ull mask = 0ull;
    int nk = 0;
    // prefetch ring, depth 2
    ull rA = 0ull, rB = 0ull;
    if (lane < ADJW) {
      if (n > 0) rA = adjc[0 * ADJW + lane];
      if (n > 1) rB = (1 < ADJC_ROWS) ? adjc[1 * ADJW + lane]
                                      : adjg[1 * ADJW + lane];
    }
    for (unsigned cc = 0; cc < n; ++cc) {
      ull rC = 0ull;
      unsigned pcc = cc + 2;
      if (lane < ADJW && pcc < n)
        rC = (pcc < ADJC_ROWS) ? adjc[pcc * ADJW + lane]
                               : adjg[(size_t)pcc * ADJW + lane];
      const int w = (int)(cc >> 6);
      ull mw = (ull)__shfl((long long)mask, w, 64);
      bool sup = (mw >> (cc & 63u)) & 1ull;
      if (!sup) {
        mask |= rA;                         // row cc (self bit harmless)
        if (lane == 0) keptcc[nk] = (int)cc;
        ++nk;
        if (nk == MAX_OUT) break;
      }
      rA = rB; rB = rC;
    }
    if (lane == 0) knum = nk;
  }
  __syncthreads();
  const int kn = knum;

  // ---- wave-parallel class argmax (R6-proven packing/tie-break) ----
  {
    const int wv = t >> 6, lane = t & 63;
    for (int kidx = wv; kidx < kn; kidx += 16) {
      ull key = sk[keptcc[kidx]];
      unsigned r = 0xFFFFFFFFu - (unsigned)(key & 0xFFFFFFFFull);
      const float* rp = x + (size_t)r * 85;
      float l0 = rp[5 + lane];
      unsigned b0 = __float_as_uint(l0);
      b0 = (b0 & 0x80000000u) ? ~b0 : (b0 | 0x80000000u);
      ull kv = ((ull)b0 << 32) | (ull)(0xFFFFFFFFu - lane);
      if (lane < 16) {
        float l1 = rp[5 + 64 + lane];
        unsigned b1 = __float_as_uint(l1);
        b1 = (b1 & 0x80000000u) ? ~b1 : (b1 | 0x80000000u);
        ull kv1 = ((ull)b1 << 32) | (ull)(0xFFFFFFFFu - (64 + lane));
        if (kv1 > kv) kv = kv1;
      }
      #pragma unroll
      for (int d = 32; d >= 1; d >>= 1) {
        ull o = (ull)__shfl_xor((long long)kv, d, 64);
        if (o > kv) kv = o;
      }
      if (lane == 0)
        kcls[kidx] = (int)(0xFFFFFFFFu - (unsigned)(kv & 0xFFFFFFFFull));
    }
  }
  __syncthreads();

  // ---- outputs: [0..99] conf, [100..499] boxes (100,4), [500..599] classes ----
  if (t < MAX_OUT) {
    float conf = 0.f; float4 bb = make_float4(0.f, 0.f, 0.f, 0.f); float cf = -1.f;
    if (t < kn) {
      int cc = keptcc[t];
      ull key = sk[cc];
      conf = __uint_as_float((unsigned)(key >> 32));
      bb = cboxg[cc];
      cf = (float)kcls[t];
    }
    out[t] = conf;
    ((float4*)(out + 100))[t] = bb;
    out[500 + t] = cf;
  }
}

// ---------------------------------------------------------------------------
extern "C" void kernel_launch(void* const* d_in, const int* in_sizes, int n_in,
                              void* d_out, int out_size, void* d_ws, size_t ws_size,
                              hipStream_t stream) {
  const float* x       = (const float*)d_in[0];
  const float* anchors = (const float*)d_in[1];
  float* out = (float*)d_out;
  char* ws = (char*)d_ws;

  float*    scores = (float*)(ws + WS_SCORES);
  unsigned* part   = (unsigned*)(ws + WS_PART);
  unsigned* cnt    = (unsigned*)(ws + WS_CNT);
  ull*      keys   = (ull*)(ws + WS_KEYS);
  ull*      sorted = (ull*)(ws + WS_SORT);
  float4*   cboxg  = (float4*)(ws + WS_CBOX);
  ull*      adj    = (ull*)(ws + WS_ADJ);

  hipLaunchKernelGGL(decode_score, dim3(NROW / 256), dim3(256),
                     0, stream, x, scores);
  hipLaunchKernelGGL(hist_kernel, dim3(HIST_BLOCKS), dim3(1024),
                     0, stream, scores, part);
  hipLaunchKernelGGL(thresh_kernel, dim3(1), dim3(1024), 0, stream, part, cnt);
  hipLaunchKernelGGL(compact_kernel, dim3(NROW / 1024), dim3(256),
                     0, stream, scores, cnt, keys);
  hipLaunchKernelGGL(rank_kernel, dim3(MAXN / 64), dim3(64),
                     0, stream, x, anchors, cnt, keys, sorted, cboxg);
  hipLaunchKernelGGL(adj_kernel, dim3(MAXN), dim3(256),
                     0, stream, cnt, cboxg, adj);
  hipLaunchKernelGGL(final_kernel, dim3(1), dim3(1024), 0, stream,
                     x, cnt, sorted, cboxg, adj, out);
}